// Round 6
// baseline (637.110 us; speedup 1.0000x reference)
//
#include <hip/hip_runtime.h>

// TemporalLSTM round 6 (gfx950): in-register recurrence, 8 batches/wave,
// pointwise split across column-halves + shfl h-exchange -> 2 independent
// waves/SIMD with NO increase in per-SIMD transcendental work.
//
// x[16384,200,5] fp32 -> LSTM(H=32, gates i,f,g,o) -> h_200 @ W_fc^T + b_fc -> out[16384,2]
//
// From R5: A = weights (resident VGPR frags), B = activations. Gate-row permutation
//   tile t8 = hb*4+g :  row m -> R = 32g + 8*(m>>2) + 4*hb + (m&3)
// gives C/D (m=4q+r, n): acc[hb*4+g][r] = gate g, batch col n, j = 8q+4hb+r,
// and the B-frag (B[k][n], k=8q'+kk) needs h[n][k] -- produced in-lane.
// R6 delta: blocks now own 8 batches (cols n and n+8 duplicate batch n&7; the
// duplicate columns read the same LDS x-frags via broadcast). Lane (n16,q) does
// pointwise only for half = n16>>3: cells j = 8q+4*half+r, r=0..3 (4 cells/lane,
// 40 trans/wave-step vs 80 in R5). Partner lane n16^8 holds the other 4 h values
// of the same column -> 4x __shfl_xor + cndmask assembles the full B-frag.
// No barriers in the step loop; 2048 single-wave blocks = 2 independent waves/SIMD.
//
// Numerics identical to R2-R5: split-bf16 (hi + residual lo) GEMM keeping
// Whi*Bhi + Whi*Blo + Wlo*Bhi (fp32 acc), x-proj + bias in one K<=17 mfma
// (k0-4 xh*Wih_hi | k5-9 xl*Wih_hi | k10-14 xh*Wih_lo | k15 1*bias_hi |
//  k16 (quad2) 1*bias_lo), exp2/rcp sigmoid+tanh.

typedef __bf16 bf16x8 __attribute__((ext_vector_type(8)));
typedef float  f32x4  __attribute__((ext_vector_type(4)));
typedef unsigned int u32;

constexpr int kT = 200, kIN = 5, kH = 32;
constexpr int CT = 40;   // timesteps of x staged per phase (200 = 5*40)

union FragU { bf16x8 v; __bf16 b[8]; unsigned short s[8]; u32 u[4]; uint4 q4; };

__device__ __forceinline__ unsigned short bfbits(__bf16 b) {
    union { __bf16 b; unsigned short s; } u; u.b = b; return u.s;
}
__device__ __forceinline__ void split2(float x, __bf16& hi, __bf16& lo) {
    hi = (__bf16)x;                 // RNE cvt
    lo = (__bf16)(x - (float)hi);   // residual, |lo| <= 2^-9 |x|
}
__device__ __forceinline__ float sigm(float z) {
    return __builtin_amdgcn_rcpf(1.0f + __builtin_amdgcn_exp2f(-1.4426950408889634f * z));
}
__device__ __forceinline__ float tanhv(float z) {
    return fmaf(2.0f,
        __builtin_amdgcn_rcpf(1.0f + __builtin_amdgcn_exp2f(-2.8853900817779268f * z)),
        -1.0f);
}

__global__ __launch_bounds__(64) void lstm_reg2(
    const float* __restrict__ x,     // [B,200,5]
    const float* __restrict__ W_ih,  // [128,5]
    const float* __restrict__ W_hh,  // [128,32]
    const float* __restrict__ b_ih,  // [128]
    const float* __restrict__ b_hh,  // [128]
    const float* __restrict__ W_fc,  // [2,32]
    const float* __restrict__ b_fc,  // [2]
    float* __restrict__ out)         // [B,2]
{
    __shared__ uint4 xbuf[CT][18];   // cols 0..15: x B-frags (8 batches x 2 quads);
                                     // col 16: k16 one-quad, col 17: zero quad

    const int lane = threadIdx.x;    // single-wave block
    const int n16  = lane & 15;
    const int q    = lane >> 4;
    const int half = n16 >> 3;       // which 4-j group this lane's pointwise owns
    const int bb   = n16 & 7;        // batch within block
    const int b0   = blockIdx.x * 8;

    // ---- weight A-frags resident in VGPRs (A[m][k]: m = lane&15, k = q*8+j) ----
    bf16x8 whhA_h[8], whhA_l[8], wihA[8];
#pragma unroll
    for (int t8 = 0; t8 < 8; ++t8) {
        const int g  = t8 & 3, hb = t8 >> 2;
        const int R  = g * 32 + 8 * (n16 >> 2) + 4 * hb + (n16 & 3);  // gate row
        FragU H, L;
#pragma unroll
        for (int j = 0; j < 8; ++j)
            split2(W_hh[R * kH + q * 8 + j], H.b[j], L.b[j]);
        whhA_h[t8] = H.v; whhA_l[t8] = L.v;

        float wr[5];
#pragma unroll
        for (int i = 0; i < 5; ++i) wr[i] = W_ih[R * kIN + i];
        __bf16 bh, bl;
        split2(b_ih[R] + b_hh[R], bh, bl);

        FragU F;
        F.u[0] = F.u[1] = F.u[2] = F.u[3] = 0u;
        if (q == 0) {                       // k0..7
#pragma unroll
            for (int i = 0; i < 5; ++i) F.b[i] = (__bf16)wr[i];       // k0..4: Wih_hi
#pragma unroll
            for (int i = 0; i < 3; ++i) F.b[5 + i] = (__bf16)wr[i];   // k5..7: Wih_hi(0..2)
        } else if (q == 1) {                // k8..15
            F.b[0] = (__bf16)wr[3];                                   // k8:  Wih_hi(3)
            F.b[1] = (__bf16)wr[4];                                   // k9:  Wih_hi(4)
#pragma unroll
            for (int i = 0; i < 5; ++i) {                             // k10..14: Wih_lo
                __bf16 hbb, lbb; split2(wr[i], hbb, lbb);
                F.b[2 + i] = lbb;
            }
            F.b[7] = bh;                                              // k15: bias_hi
        } else if (q == 2) {
            F.b[0] = bl;                                              // k16: bias_lo
        }
        wihA[t8] = F.v;
    }

    // ---- const x-frag quads (written once) ----
    for (int t2 = lane; t2 < CT; t2 += 64) {
        xbuf[t2][16] = make_uint4(0x3F80u, 0u, 0u, 0u);   // quad2: k16 B=1.0 (bf16)
        xbuf[t2][17] = make_uint4(0u, 0u, 0u, 0u);        // quad3: zeros
    }

    const int col = (q < 2) ? (bb * 2 + q) : (14 + q);    // loop-invariant frag column
    const f32x4 zf4 = {0.f, 0.f, 0.f, 0.f};

    // recurrence state, in registers: this lane's 4 cells (batch bb, j = 8q+4*half+r)
    float c4s[4] = {0.f, 0.f, 0.f, 0.f};
    float hf[4]  = {0.f, 0.f, 0.f, 0.f};
    FragU Bh, Bl;                          // assembled h B-frags (own + partner)
    Bh.u[0] = Bh.u[1] = Bh.u[2] = Bh.u[3] = 0u;
    Bl.u[0] = Bl.u[1] = Bl.u[2] = Bl.u[3] = 0u;

    f32x4 xn[8];                           // pipelined x-proj + bias

    for (int phase = 0; phase < kT / CT; ++phase) {
        // ---- stage CT steps of x as ready-made B-frags (64 lanes, 8 batches) ----
        {
            const int mm = lane >> 3, pp = lane & 7;      // batch row, 5-step chunk
            const float* xrow = x + (size_t)(b0 + mm) * (kT * kIN)
                                  + (size_t)(phase * CT + pp * 5) * kIN;
            float xv[25];
#pragma unroll
            for (int i = 0; i < 25; ++i) xv[i] = xrow[i];
#pragma unroll
            for (int s5 = 0; s5 < 5; ++s5) {
                u32 xh[5], xl[5];
#pragma unroll
                for (int i = 0; i < 5; ++i) {
                    __bf16 hbb, lbb; split2(xv[s5 * 5 + i], hbb, lbb);
                    xh[i] = bfbits(hbb); xl[i] = bfbits(lbb);
                }
                uint4 f0 = make_uint4(xh[0] | (xh[1] << 16),
                                      xh[2] | (xh[3] << 16),
                                      xh[4] | (xl[0] << 16),
                                      xl[1] | (xl[2] << 16));
                uint4 f1 = make_uint4(xl[3] | (xl[4] << 16),
                                      xh[0] | (xh[1] << 16),
                                      xh[2] | (xh[3] << 16),
                                      xh[4] | (0x3F80u << 16));   // k15: B = 1.0
                const int tc = pp * 5 + s5;
                xbuf[tc][mm * 2 + 0] = f0;
                xbuf[tc][mm * 2 + 1] = f1;
            }
        }
        __syncthreads();   // single-wave block: lgkmcnt drain

        // x-proj for the first step of this phase
        {
            FragU xg; xg.q4 = xbuf[0][col];
#pragma unroll
            for (int t8 = 0; t8 < 8; ++t8)
                xn[t8] = __builtin_amdgcn_mfma_f32_16x16x32_bf16(wihA[t8], xg.v, zf4, 0, 0, 0);
        }

#pragma unroll 1
        for (int tc = 0; tc < CT; ++tc) {
            // h-dependent GEMM: 3 mfma per tile, acc init = precomputed x-proj+bias
            f32x4 acc[8];
#pragma unroll
            for (int t8 = 0; t8 < 8; ++t8) {
                f32x4 a = __builtin_amdgcn_mfma_f32_16x16x32_bf16(whhA_h[t8], Bh.v, xn[t8], 0, 0, 0);
                a = __builtin_amdgcn_mfma_f32_16x16x32_bf16(whhA_h[t8], Bl.v, a, 0, 0, 0);
                a = __builtin_amdgcn_mfma_f32_16x16x32_bf16(whhA_l[t8], Bh.v, a, 0, 0, 0);
                acc[t8] = a;
            }

            // prefetch next step's x-proj (h-independent)
            {
                const int tn = (tc + 1 < CT) ? tc + 1 : 0;
                FragU xg; xg.q4 = xbuf[tn][col];
#pragma unroll
                for (int t8 = 0; t8 < 8; ++t8)
                    xn[t8] = __builtin_amdgcn_mfma_f32_16x16x32_bf16(wihA[t8], xg.v, zf4, 0, 0, 0);
            }

            // select this lane's half of the accs (4 gates x 4 cells)
            f32x4 av[4];
#pragma unroll
            for (int g = 0; g < 4; ++g) av[g] = half ? acc[4 + g] : acc[g];

            // pointwise: 4 cells/lane (batch bb, j = 8q + 4*half + r)
            u32 ph[4], pl[4];
#pragma unroll
            for (int r = 0; r < 4; ++r) {
                float iv = sigm (av[0][r]);
                float fv = sigm (av[1][r]);
                float gv = tanhv(av[2][r]);
                float ov = sigm (av[3][r]);
                float cn = fmaf(fv, c4s[r], iv * gv);
                c4s[r] = cn;
                float hn = ov * tanhv(cn);
                hf[r] = hn;
                __bf16 hh, hl;
                split2(hn, hh, hl);
                ph[r] = bfbits(hh); pl[r] = bfbits(hl);
            }
            // pack own 4 cells: (r0,r1) and (r2,r3)
            u32 oh0 = ph[0] | (ph[1] << 16), oh1 = ph[2] | (ph[3] << 16);
            u32 ol0 = pl[0] | (pl[1] << 16), ol1 = pl[2] | (pl[3] << 16);
            // exchange with partner lane (n16 ^ 8): other 4 h of this column
            u32 sh0 = (u32)__shfl_xor((int)oh0, 8);
            u32 sh1 = (u32)__shfl_xor((int)oh1, 8);
            u32 sl0 = (u32)__shfl_xor((int)ol0, 8);
            u32 sl1 = (u32)__shfl_xor((int)ol1, 8);
            // B-frag kk0..3 = half-0 cells, kk4..7 = half-1 cells
            Bh.u[0] = half ? sh0 : oh0;
            Bh.u[1] = half ? sh1 : oh1;
            Bh.u[2] = half ? oh0 : sh0;
            Bh.u[3] = half ? oh1 : sh1;
            Bl.u[0] = half ? sl0 : ol0;
            Bl.u[1] = half ? sl1 : ol1;
            Bl.u[2] = half ? ol0 : sl0;
            Bl.u[3] = half ? ol1 : sl1;
        }
    }

    // ---- epilogue: every lane holds 4 distinct final h values ----
    // h[batch bb][j = 8q + 4*half + r] = hf[r]
    __syncthreads();
    float* hfin = (float*)xbuf;            // reuse LDS: [8][33] f32
#pragma unroll
    for (int r = 0; r < 4; ++r)
        hfin[bb * 33 + q * 8 + 4 * half + r] = hf[r];
    __syncthreads();
    if (lane < 16) {
        const int m = lane >> 1, o = lane & 1;
        float s = b_fc[o];
#pragma unroll
        for (int j = 0; j < kH; ++j)
            s = fmaf(hfin[m * 33 + j], W_fc[o * kH + j], s);
        out[(size_t)(b0 + m) * 2 + o] = s;
    }
}

extern "C" void kernel_launch(void* const* d_in, const int* in_sizes, int n_in,
                              void* d_out, int out_size, void* d_ws, size_t ws_size,
                              hipStream_t stream) {
    const float* x    = (const float*)d_in[0];
    const float* W_ih = (const float*)d_in[1];
    const float* W_hh = (const float*)d_in[2];
    const float* b_ih = (const float*)d_in[3];
    const float* b_hh = (const float*)d_in[4];
    const float* W_fc = (const float*)d_in[5];
    const float* b_fc = (const float*)d_in[6];
    float* out = (float*)d_out;

    // 16384 batches / 8 per wave = 2048 single-wave blocks (2 waves/SIMD)
    hipLaunchKernelGGL(lstm_reg2, dim3(2048), dim3(64), 0, stream,
                       x, W_ih, W_hh, b_ih, b_hh, W_fc, b_fc, out);
}